// Round 1
// 500.855 us; speedup vs baseline: 1.0397x; 1.0397x over previous
//
#include <hip/hip_runtime.h>

// GTConv fused: filt = softmax(weight, axis=0)  [R=8, C=4]
// d_out (float32, concat):
//   out0 [2, R*E] at offset 0      : out0[s, j*E+e] = (float)edge_index[j, s, e]
//   out1 [C, R*E] at offset 2*R*E  : out1[i, j*E+e] = filt[j,i] * edge_value[j,e]
// Single kernel: every input byte read once, every output byte written once.
// All traffic is pure streaming -> nontemporal loads/stores (no L2/LLC pollution).

#define GT_E  2000000
#define GT_R  8
#define GT_C  4
#define GT_RE (GT_R * GT_E)        // 16,000,000
#define GT_E4 (GT_E / 4)           // 500,000 float4-chunks per relation j
#define GT_CHUNKS (GT_R * GT_E4)   // 4,000,000 chunks total

typedef float f32x4 __attribute__((ext_vector_type(4)));
typedef int   i32x4 __attribute__((ext_vector_type(4)));

__global__ __launch_bounds__(256) void gt_fused_kernel(const float* __restrict__ w,
                                                       const int*   __restrict__ idx,
                                                       const float* __restrict__ ev,
                                                       float*       __restrict__ out) {
    __shared__ float filt[GT_R * GT_C];
    if (threadIdx.x < GT_C) {
        int i = threadIdx.x;
        float col[GT_R];
        float m = -1e30f;
        #pragma unroll
        for (int j = 0; j < GT_R; ++j) { col[j] = w[j * GT_C + i]; m = fmaxf(m, col[j]); }
        float sum = 0.f;
        #pragma unroll
        for (int j = 0; j < GT_R; ++j) { col[j] = expf(col[j] - m); sum += col[j]; }
        float inv = 1.f / sum;
        #pragma unroll
        for (int j = 0; j < GT_R; ++j) filt[j * GT_C + i] = col[j] * inv;
    }
    __syncthreads();

    const int stride = (int)gridDim.x * 256;
    for (int c = (int)blockIdx.x * 256 + (int)threadIdx.x; c < GT_CHUNKS; c += stride) {
        const int j  = c / GT_E4;              // magic-mul, no HW div
        const int e  = (c - j * GT_E4) * 4;
        const int in_base = j * (2 * GT_E) + e;   // edge_index laid out [R, 2, E]
        const int je      = j * GT_E + e;         // shared output sub-offset

        // ---- loads: each input byte touched exactly once ----
        const i32x4 i0 = __builtin_nontemporal_load((const i32x4*)(idx + in_base));          // s=0
        const i32x4 i1 = __builtin_nontemporal_load((const i32x4*)(idx + in_base + GT_E));   // s=1
        const f32x4 v  = __builtin_nontemporal_load((const f32x4*)(ev + je));

        // ---- out0: permuted int->float copy ----
        const f32x4 a = __builtin_convertvector(i0, f32x4);
        const f32x4 b = __builtin_convertvector(i1, f32x4);
        __builtin_nontemporal_store(a, (f32x4*)(out + je));
        __builtin_nontemporal_store(b, (f32x4*)(out + GT_RE + je));

        // ---- out1: 4 channel planes, ev read once, broadcast-scaled ----
        const float f0 = filt[j * GT_C + 0];
        const float f1 = filt[j * GT_C + 1];
        const float f2 = filt[j * GT_C + 2];
        const float f3 = filt[j * GT_C + 3];
        __builtin_nontemporal_store(v * f0, (f32x4*)(out + 2 * GT_RE + je));
        __builtin_nontemporal_store(v * f1, (f32x4*)(out + 3 * GT_RE + je));
        __builtin_nontemporal_store(v * f2, (f32x4*)(out + 4 * GT_RE + je));
        __builtin_nontemporal_store(v * f3, (f32x4*)(out + 5 * GT_RE + je));
    }
}

extern "C" void kernel_launch(void* const* d_in, const int* in_sizes, int n_in,
                              void* d_out, int out_size, void* d_ws, size_t ws_size,
                              hipStream_t stream) {
    const float* weight     = (const float*)d_in[0];
    const int*   edge_index = (const int*)d_in[1];   // int inputs staged as int32
    const float* edge_value = (const float*)d_in[2];
    float* out = (float*)d_out;

    // 2048 blocks = 8 blocks/CU * 256 CU -> full 32-wave occupancy; grid-stride
    // covers 4M chunks (~7.6 iterations/thread).
    gt_fused_kernel<<<2048, 256, 0, stream>>>(weight, edge_index, edge_value, out);
}